// Round 1
// baseline (481.855 us; speedup 1.0000x reference)
//
#include <hip/hip_runtime.h>

// Cosine similarity per row: q,d are [N, 256] fp32; out is [N] fp32.
// One 64-lane wave per row: lane i loads float4 at column 4*i (16 B/lane,
// 1 KiB/wave, perfectly coalesced), accumulates qq/dd/qd partials, then a
// width-64 shuffle reduction. Memory-bound: 512 MiB in, 1 MiB out.
__global__ __launch_bounds__(256) void cosine_rows_kernel(
    const float* __restrict__ q,
    const float* __restrict__ d,
    float* __restrict__ out,
    int n_rows)
{
    const int gtid = blockIdx.x * blockDim.x + threadIdx.x;
    const int row  = gtid >> 6;          // one wave (64 lanes) per row
    const int lane = threadIdx.x & 63;
    if (row >= n_rows) return;

    const float4* qrow = reinterpret_cast<const float4*>(q + (size_t)row * 256);
    const float4* drow = reinterpret_cast<const float4*>(d + (size_t)row * 256);

    float4 qv = qrow[lane];
    float4 dv = drow[lane];

    float qq = qv.x * qv.x + qv.y * qv.y + qv.z * qv.z + qv.w * qv.w;
    float dd = dv.x * dv.x + dv.y * dv.y + dv.z * dv.z + dv.w * dv.w;
    float qd = qv.x * dv.x + qv.y * dv.y + qv.z * dv.z + qv.w * dv.w;

    // Wave-64 reduction (wavefront = 64 on CDNA, not 32).
    #pragma unroll
    for (int off = 32; off > 0; off >>= 1) {
        qq += __shfl_down(qq, off, 64);
        dd += __shfl_down(dd, off, 64);
        qd += __shfl_down(qd, off, 64);
    }

    if (lane == 0) {
        out[row] = qd * rsqrtf(qq * dd);
    }
}

extern "C" void kernel_launch(void* const* d_in, const int* in_sizes, int n_in,
                              void* d_out, int out_size, void* d_ws, size_t ws_size,
                              hipStream_t stream) {
    const float* q = (const float*)d_in[0];
    const float* d = (const float*)d_in[1];
    float* out = (float*)d_out;

    const int D = 256;
    const int n_rows = in_sizes[0] / D;   // 262144

    // 256 threads = 4 waves = 4 rows per block.
    const int rows_per_block = 4;
    const int grid = (n_rows + rows_per_block - 1) / rows_per_block;

    cosine_rows_kernel<<<grid, 256, 0, stream>>>(q, d, out, n_rows);
}